// Round 11
// baseline (407.549 us; speedup 1.0000x reference)
//
#include <hip/hip_runtime.h>
#include <hip/hip_bf16.h>

#define D_EMB 128
#define T_HIST 200
#define T_PAD 208
#define NG 6400      // f32x4 granules per batch row
#define ITERS 64
#define NBLK 256

typedef float f32x4 __attribute__((ext_vector_type(4)));
typedef short bf16x8 __attribute__((ext_vector_type(8)));

__device__ __forceinline__ short f2bf(float f) {
    unsigned u = __builtin_bit_cast(unsigned, f);
    u += 0x7fffu + ((u >> 16) & 1u);
    return (short)(u >> 16);
}

// Barrier publishing LDS only (lgkmcnt(0)+s_barrier) — no vmcnt drain, so
// global register loads stay in flight across it (proven harmless in R10).
__device__ __forceinline__ void wg_barrier() {
    asm volatile("s_waitcnt lgkmcnt(0)" ::: "memory");
    __builtin_amdgcn_s_barrier();
}

// proven DPP 16-lane-group sum
__device__ __forceinline__ float dpp_reduce16(float x) {
    int v = __builtin_bit_cast(int, x);
    x += __builtin_bit_cast(float, __builtin_amdgcn_update_dpp(0, v, 0xB1, 0xF, 0xF, true));
    v = __builtin_bit_cast(int, x);
    x += __builtin_bit_cast(float, __builtin_amdgcn_update_dpp(0, v, 0x4E, 0xF, 0xF, true));
    v = __builtin_bit_cast(int, x);
    x += __builtin_bit_cast(float, __builtin_amdgcn_update_dpp(0, v, 0x141, 0xF, 0xF, true));
    v = __builtin_bit_cast(int, x);
    x += __builtin_bit_cast(float, __builtin_amdgcn_update_dpp(0, v, 0x140, 0xF, 0xF, true));
    return x;
}

// f32x4 granule -> 4 packed RNE bf16 (8B)
__device__ __forceinline__ uint2 cvt_granule(f32x4 v) {
    uint2 r;
    asm("v_cvt_pk_bf16_f32 %0, %1, %2" : "=v"(r.x) : "v"(v[0]), "v"(v[1]));
    asm("v_cvt_pk_bf16_f32 %0, %1, %2" : "=v"(r.y) : "v"(v[2]), "v"(v[3]));
    return r;
}

__global__ void pack_w_kernel(const float* __restrict__ W, short* __restrict__ wfrag) {
    int tid = blockIdx.x * blockDim.x + threadIdx.x;
    int fragid = tid >> 6;
    int lane = tid & 63;
    int ks = fragid >> 3;
    int nt = fragid & 7;
    int n = nt * 16 + (lane & 15);
    int k0 = ks * 32 + (lane >> 4) * 8;
    bf16x8 r;
#pragma unroll
    for (int j = 0; j < 8; ++j) r[j] = f2bf(W[(k0 + j) * D_EMB + n]);
    ((bf16x8*)wfrag)[fragid * 64 + lane] = r;
}

__global__ void tw_kernel(const float* __restrict__ target, const float* __restrict__ W,
                          const float* __restrict__ bias, float* __restrict__ TW) {
    int e = threadIdx.x;
    int b0 = blockIdx.x * 8;
    float bv = bias[e];
    float acc[8];
#pragma unroll
    for (int i = 0; i < 8; ++i) acc[i] = bv;
    for (int d = 0; d < D_EMB; ++d) {
        float wv = W[d * D_EMB + e];
#pragma unroll
        for (int i = 0; i < 8; ++i)
            acc[i] = fmaf(target[(size_t)(b0 + i) * D_EMB + d], wv, acc[i]);
    }
#pragma unroll
    for (int i = 0; i < 8; ++i) TW[(size_t)(b0 + i) * D_EMB + e] = acc[i];
}

// R10's kernel (wg_barrier, proven data path) with the BODY reordered to
// R7's runway-maximizing schedule: MFMA -> softmax -> pass2 -> out ->
// issue(i+2) -> commit(i+1) -> barrier. The commit's counted vmcnt wait on
// tile i+1's loads now sits a FULL BODY (~5us) after their issue (end of
// body i-1), covering HBM latency + service (~4.5us) -> commit stall ~0.
__launch_bounds__(512, 2)
__global__ void attn_main(const float* __restrict__ hist,
                          const float* __restrict__ TW,
                          const float* __restrict__ q,
                          const short* __restrict__ wfrag,
                          float* __restrict__ out) {
    __shared__ __align__(16) uint2 h2[2][T_PAD * 32];  // 2 x 53248 B bf16 tiles
    __shared__ float s_tw[2][D_EMB];
    __shared__ float s_logits[2][T_PAD];
    __shared__ float s_scores[T_PAD];
    __shared__ float s_red[16];
    __shared__ float s_p2[16][D_EMB];

    const int tid = threadIdx.x;
    const int l = tid & 63;
    const int w = tid >> 6;
    const int p = w & 3;
    const int hf = w >> 2;
    const int l15 = l & 15;
    const int lg = l >> 4;
    const int r = tid >> 5;
    const int cc = tid & 31;
    const int c_log = (((cc >> 1) ^ (r & 7)) << 1) | (cc & 1);
    const int base_g = r * 32 + c_log;  // + k*512 per k
    const f32x4 vzero = {0.f, 0.f, 0.f, 0.f};

    bf16x8 Bf[4][4];
#pragma unroll
    for (int ks = 0; ks < 4; ++ks)
#pragma unroll
        for (int j = 0; j < 4; ++j)
            Bf[ks][j] = ((const bf16x8*)wfrag)[(ks * 8 + hf * 4 + j) * 64 + l];

    float qv[4];
#pragma unroll
    for (int j = 0; j < 4; ++j) qv[j] = q[hf * 64 + j * 16 + l15];

    // zero pad rows (t=200..207 live at half-granules [6400,6656)) in both buffers
    if (tid >= 256) {
        h2[0][6144 + tid] = uint2{0u, 0u};
        h2[1][6144 + tid] = uint2{0u, 0u};
    }

    const int base = blockIdx.x * ITERS;
    const f32x4* ghist = (const f32x4*)hist;

    f32x4 stgA[13], stgB[13];
    float twA = 0.f, twB = 0.f;

    {   // prologue: load tile 0 + issue tile 1
        const f32x4* g0 = ghist + (size_t)base * NG + base_g;
#pragma unroll
        for (int k = 0; k < 12; ++k) stgA[k] = g0[k * 512];
        if (tid < 256) stgA[12] = g0[12 * 512];
        if (tid < 128) twA = TW[(size_t)base * D_EMB + tid];
        const f32x4* g1 = ghist + (size_t)(base + 1) * NG + base_g;
#pragma unroll
        for (int k = 0; k < 12; ++k) stgB[k] = g1[k * 512];
        if (tid < 256) stgB[12] = g1[12 * 512];
        if (tid < 128) twB = TW[(size_t)(base + 1) * D_EMB + tid];
    }
    {   // commit tile 0 -> h2[0]
        uint2* d = h2[0];
#pragma unroll
        for (int k = 0; k < 12; ++k) d[tid + k * 512] = cvt_granule(stgA[k]);
        if (tid < 256) d[tid + 12 * 512] = cvt_granule(stgA[12]);
        if (tid < 128) s_tw[0][tid] = twA;
    }
    wg_barrier();

#define BODY(PAR, STG_CUR, STG_OTH, TW_CUR, TW_OTH, II)                           \
    {                                                                             \
        const int bb = base + (II);                                               \
        float twv[4];                                                             \
        _Pragma("unroll") for (int j = 0; j < 4; ++j)                             \
            twv[j] = s_tw[PAR][hf * 64 + j * 16 + l15];                           \
        const bf16x8* hp = (const bf16x8*)h2[PAR];                                \
        for (int mt = p; mt < 13; mt += 4) {                                      \
            f32x4 acc[4];                                                         \
            _Pragma("unroll") for (int j = 0; j < 4; ++j) acc[j] = vzero;         \
            _Pragma("unroll") for (int ks = 0; ks < 4; ++ks) {                    \
                bf16x8 A = hp[l15 * 16 + ((ks * 4 + lg) ^ (l15 & 7)) + mt * 256]; \
                _Pragma("unroll") for (int j = 0; j < 4; ++j)                     \
                    acc[j] = __builtin_amdgcn_mfma_f32_16x16x32_bf16(             \
                        A, Bf[ks][j], acc[j], 0, 0, 0);                           \
            }                                                                     \
            float part[4] = {0.f, 0.f, 0.f, 0.f};                                 \
            _Pragma("unroll") for (int j = 0; j < 4; ++j) {                       \
                _Pragma("unroll") for (int rr = 0; rr < 4; ++rr)                  \
                    part[rr] += fmaxf(acc[j][rr] + twv[j], 0.f) * qv[j];          \
            }                                                                     \
            _Pragma("unroll") for (int rr = 0; rr < 4; ++rr)                      \
                part[rr] = dpp_reduce16(part[rr]);                                \
            if (l15 == 0) {                                                       \
                int row = mt * 16 + lg * 4;                                       \
                f32x4 v;                                                          \
                _Pragma("unroll") for (int rr = 0; rr < 4; ++rr)                  \
                    v[rr] = (row + rr < T_HIST) ? part[rr] : -1e30f;              \
                *(f32x4*)&s_logits[hf][row] = v;                                  \
            }                                                                     \
        }                                                                         \
        wg_barrier();                                                             \
        float lv = (tid < T_PAD) ? (s_logits[0][tid] + s_logits[1][tid]) : -1e30f;\
        float m = lv;                                                             \
        _Pragma("unroll") for (int off = 32; off >= 1; off >>= 1)                 \
            m = fmaxf(m, __shfl_xor(m, off, 64));                                 \
        if (l == 0) s_red[w] = m;                                                 \
        wg_barrier();                                                             \
        float M = s_red[0];                                                       \
        _Pragma("unroll") for (int k = 1; k < 8; ++k) M = fmaxf(M, s_red[k]);     \
        float e = (tid < T_PAD) ? __expf(lv - M) : 0.f;                           \
        if (tid < T_PAD) s_scores[tid] = e;                                       \
        float sm = e;                                                             \
        _Pragma("unroll") for (int off = 32; off >= 1; off >>= 1)                 \
            sm += __shfl_xor(sm, off, 64);                                        \
        if (l == 0) s_red[8 + w] = sm;                                            \
        wg_barrier();                                                             \
        float S = s_red[8];                                                       \
        _Pragma("unroll") for (int k = 9; k < 16; ++k) S += s_red[k];             \
        /* pass 2 from exact f32 registers (tile II) — frees STG_CUR */           \
        f32x4 acc2 = vzero;                                                       \
        _Pragma("unroll") for (int k = 0; k < 12; ++k) {                          \
            float sc = s_scores[r + 16 * k];                                      \
            _Pragma("unroll") for (int rr = 0; rr < 4; ++rr)                      \
                acc2[rr] = fmaf(sc, STG_CUR[k][rr], acc2[rr]);                    \
        }                                                                         \
        if (tid < 256) {                                                          \
            float sc = s_scores[r + 192];                                         \
            _Pragma("unroll") for (int rr = 0; rr < 4; ++rr)                      \
                acc2[rr] = fmaf(sc, STG_CUR[12][rr], acc2[rr]);                   \
        }                                                                         \
        *(f32x4*)&s_p2[r][c_log * 4] = acc2;                                      \
        wg_barrier();                                                             \
        if (tid < 128) {                                                          \
            float o = 0.f;                                                        \
            _Pragma("unroll") for (int k = 0; k < 16; ++k) o += s_p2[k][tid];     \
            out[(size_t)bb * D_EMB + tid] = o / S;                                \
        }                                                                         \
        /* issue loads for tile II+2 into the just-freed STG_CUR */               \
        if ((II) + 2 < ITERS) {                                                   \
            const f32x4* gn = ghist + (size_t)(bb + 2) * NG + base_g;             \
            _Pragma("unroll") for (int k = 0; k < 12; ++k) STG_CUR[k] = gn[k*512];\
            if (tid < 256) STG_CUR[12] = gn[12 * 512];                            \
            if (tid < 128) TW_CUR = TW[(size_t)(bb + 2) * D_EMB + tid];           \
        }                                                                         \
        /* commit tile II+1 at body END: its loads were issued at this same */    \
        /* point one body ago -> counted vmcnt finds them complete */             \
        if ((II) + 1 < ITERS) {                                                   \
            uint2* d = h2[1 - (PAR)];                                             \
            _Pragma("unroll") for (int k = 0; k < 12; ++k)                        \
                d[tid + k * 512] = cvt_granule(STG_OTH[k]);                       \
            if (tid < 256) d[tid + 12 * 512] = cvt_granule(STG_OTH[12]);          \
            if (tid < 128) s_tw[1 - (PAR)][tid] = TW_OTH;                         \
        }                                                                         \
        wg_barrier();                                                             \
    }

    for (int ii = 0; ii < ITERS; ii += 2) {
        BODY(0, stgA, stgB, twA, twB, ii)
        BODY(1, stgB, stgA, twB, twA, ii + 1)
    }
#undef BODY
}

extern "C" void kernel_launch(void* const* d_in, const int* in_sizes, int n_in,
                              void* d_out, int out_size, void* d_ws, size_t ws_size,
                              hipStream_t stream) {
    const float* target = (const float*)d_in[0];
    const float* hist   = (const float*)d_in[1];
    const float* Wk     = (const float*)d_in[2];
    const float* Wb     = (const float*)d_in[3];
    const float* qk     = (const float*)d_in[4];
    float* out = (float*)d_out;

    short* wfrag = (short*)d_ws;                   // 32 KB
    float* TW    = (float*)((char*)d_ws + 32768);  // 8 MB

    pack_w_kernel<<<dim3(8), dim3(256), 0, stream>>>(Wk, wfrag);
    tw_kernel<<<dim3(2048), dim3(128), 0, stream>>>(target, Wk, Wb, TW);
    attn_main<<<dim3(NBLK), dim3(512), 0, stream>>>(hist, TW, qk, wfrag, out);
}

// Round 12
// 365.594 us; speedup vs baseline: 1.1148x; 1.1148x over previous
//
#include <hip/hip_runtime.h>
#include <hip/hip_bf16.h>

#define D_EMB 128
#define T_HIST 200
#define T_PAD 208
#define NG 6400      // f32x4 granules per batch row
#define ITERS 32
#define NBLK 512     // 2 blocks per CU (pair: b and b+256)

typedef float f32x4 __attribute__((ext_vector_type(4)));
typedef short bf16x8 __attribute__((ext_vector_type(8)));

__device__ __forceinline__ short f2bf(float f) {
    unsigned u = __builtin_bit_cast(unsigned, f);
    u += 0x7fffu + ((u >> 16) & 1u);
    return (short)(u >> 16);
}

// proven DPP 16-lane-group sum
__device__ __forceinline__ float dpp_reduce16(float x) {
    int v = __builtin_bit_cast(int, x);
    x += __builtin_bit_cast(float, __builtin_amdgcn_update_dpp(0, v, 0xB1, 0xF, 0xF, true));
    v = __builtin_bit_cast(int, x);
    x += __builtin_bit_cast(float, __builtin_amdgcn_update_dpp(0, v, 0x4E, 0xF, 0xF, true));
    v = __builtin_bit_cast(int, x);
    x += __builtin_bit_cast(float, __builtin_amdgcn_update_dpp(0, v, 0x141, 0xF, 0xF, true));
    v = __builtin_bit_cast(int, x);
    x += __builtin_bit_cast(float, __builtin_amdgcn_update_dpp(0, v, 0x140, 0xF, 0xF, true));
    return x;
}

// f32x4 granule -> 4 packed RNE bf16 (8B)
__device__ __forceinline__ uint2 cvt_granule(f32x4 v) {
    uint2 r;
    asm("v_cvt_pk_bf16_f32 %0, %1, %2" : "=v"(r.x) : "v"(v[0]), "v"(v[1]));
    asm("v_cvt_pk_bf16_f32 %0, %1, %2" : "=v"(r.y) : "v"(v[2]), "v"(v[3]));
    return r;
}

__global__ void pack_w_kernel(const float* __restrict__ W, short* __restrict__ wfrag) {
    int tid = blockIdx.x * blockDim.x + threadIdx.x;
    int fragid = tid >> 6;
    int lane = tid & 63;
    int ks = fragid >> 3;
    int nt = fragid & 7;
    int n = nt * 16 + (lane & 15);
    int k0 = ks * 32 + (lane >> 4) * 8;
    bf16x8 r;
#pragma unroll
    for (int j = 0; j < 8; ++j) r[j] = f2bf(W[(k0 + j) * D_EMB + n]);
    ((bf16x8*)wfrag)[fragid * 64 + lane] = r;
}

__global__ void tw_kernel(const float* __restrict__ target, const float* __restrict__ W,
                          const float* __restrict__ bias, float* __restrict__ TW) {
    int e = threadIdx.x;
    int b0 = blockIdx.x * 8;
    float bv = bias[e];
    float acc[8];
#pragma unroll
    for (int i = 0; i < 8; ++i) acc[i] = bv;
    for (int d = 0; d < D_EMB; ++d) {
        float wv = W[d * D_EMB + e];
#pragma unroll
        for (int i = 0; i < 8; ++i)
            acc[i] = fmaf(target[(size_t)(b0 + i) * D_EMB + d], wv, acc[i]);
    }
#pragma unroll
    for (int i = 0; i < 8; ++i) TW[(size_t)(b0 + i) * D_EMB + e] = acc[i];
}

// 2-blocks/CU TLP with convoy-breaking. Data path = R9 verbatim (8-wave
// n-split, pointer-cast bf16 A reads, DPP reduce, exact-f32 pass2 from regs).
// Deltas: (1) staging split into H0 (rows 0..111, issued at body bottom) and
// H1 (rows 112..207, issued after B1) -> 4 finer HBM bursts per tile per CU;
// (2) anti-phase stagger: second-resident blocks sleep ~3.2us once at entry.
__launch_bounds__(512, 4)
__global__ void attn_main(const float* __restrict__ hist,
                          const float* __restrict__ TW,
                          const float* __restrict__ q,
                          const short* __restrict__ wfrag,
                          float* __restrict__ out) {
    __shared__ __align__(16) uint2 bufH0[3584];   // rows 0..111  (28672 B)
    __shared__ __align__(16) uint2 bufH1[3072];   // rows 112..207 (24576 B)
    __shared__ float s_tw[D_EMB];                 // 512 B
    __shared__ float s_logits[8][T_PAD];          // 6656 B
    __shared__ float s_scores[T_PAD];             // 832 B
    __shared__ float s_red[16];                   // 64 B
    __shared__ float s_p2[16][D_EMB];             // 8192 B  (total ~69.5 KB)

    const int tid = threadIdx.x;
    const int l = tid & 63;
    const int w = tid >> 6;   // wave id == n-tile id
    const int l15 = l & 15;
    const int lg = l >> 4;
    const int r = tid >> 5;
    const int cc = tid & 31;
    const int c_log = (((cc >> 1) ^ (r & 7)) << 1) | (cc & 1);
    const int base_g = r * 32 + c_log;  // + k*512 covers rows r+16k
    const f32x4 vzero = {0.f, 0.f, 0.f, 0.f};

    bf16x8 Bf[4];
#pragma unroll
    for (int ks = 0; ks < 4; ++ks)
        Bf[ks] = ((const bf16x8*)wfrag)[(ks * 8 + w) * 64 + l];
    const float qv = q[w * 16 + l15];

    // zero H1 pad rows (local rows 88..95 = t 200..207); never overwritten
    if (tid >= 256) bufH1[2560 + tid] = uint2{0u, 0u};

    // anti-phase stagger for the CU's second resident block (~3.2 us once)
    if (blockIdx.x & 256) __builtin_amdgcn_s_sleep(120);

    const int base = blockIdx.x * ITERS;
    const f32x4* ghist = (const f32x4*)hist;

    f32x4 sH0[7], sH1[6];
    float twstg = 0.f;

    {   // prologue: H0 of tile 0 + tw (H1 issued in-loop after B1)
        const f32x4* g0 = ghist + (size_t)base * NG;
#pragma unroll
        for (int k = 0; k < 7; ++k) sH0[k] = g0[base_g + k * 512];
        if (tid < 128) twstg = TW[(size_t)base * D_EMB + tid];
    }

    for (int i = 0; i < ITERS; ++i) {
        const int b = base + i;

        // ---- commit H0 (rows 0..111) ----
#pragma unroll
        for (int k = 0; k < 7; ++k) bufH0[tid + k * 512] = cvt_granule(sH0[k]);
        if (tid < 128) s_tw[tid] = twstg;
        __syncthreads();  // B1 (drains H0 loads)

        // ---- issue H1 loads for THIS tile (burst #2, separated from H0) ----
        {
            const f32x4* g1 = ghist + (size_t)b * NG;
#pragma unroll
            for (int k = 0; k < 5; ++k) sH1[k] = g1[base_g + (7 + k) * 512];
            if (tid < 256) sH1[5] = g1[base_g + 12 * 512];
        }

        const float twv = s_tw[w * 16 + l15];
        const bf16x8* hp0 = (const bf16x8*)bufH0;
        const bf16x8* hp1 = (const bf16x8*)bufH1;

        // ---- MFMA h0: mt 0..6 (rows < 200 always, no clamp) ----
        for (int mt = 0; mt < 7; ++mt) {
            f32x4 acc = vzero;
#pragma unroll
            for (int ks = 0; ks < 4; ++ks) {
                bf16x8 A = hp0[l15 * 16 + ((ks * 4 + lg) ^ (l15 & 7)) + mt * 256];
                acc = __builtin_amdgcn_mfma_f32_16x16x32_bf16(A, Bf[ks], acc, 0, 0, 0);
            }
            float part[4];
#pragma unroll
            for (int rr = 0; rr < 4; ++rr)
                part[rr] = fmaxf(acc[rr] + twv, 0.f) * qv;
#pragma unroll
            for (int rr = 0; rr < 4; ++rr) part[rr] = dpp_reduce16(part[rr]);
            if (l15 == 0) {
                f32x4 v;
#pragma unroll
                for (int rr = 0; rr < 4; ++rr) v[rr] = part[rr];
                *(f32x4*)&s_logits[w][mt * 16 + lg * 4] = v;
            }
        }

        // ---- commit H1 (rows 112..199; pads pre-zeroed) ----
#pragma unroll
        for (int k = 0; k < 5; ++k) bufH1[tid + k * 512] = cvt_granule(sH1[k]);
        if (tid < 256) bufH1[tid + 5 * 512] = cvt_granule(sH1[5]);
        __syncthreads();  // B2 (drains H1 loads)

        // ---- MFMA h1: mt 7..12 (clamp rows >= 200) ----
        for (int mt = 7; mt < 13; ++mt) {
            f32x4 acc = vzero;
#pragma unroll
            for (int ks = 0; ks < 4; ++ks) {
                bf16x8 A = hp1[l15 * 16 + ((ks * 4 + lg) ^ (l15 & 7)) + (mt - 7) * 256];
                acc = __builtin_amdgcn_mfma_f32_16x16x32_bf16(A, Bf[ks], acc, 0, 0, 0);
            }
            float part[4];
#pragma unroll
            for (int rr = 0; rr < 4; ++rr)
                part[rr] = fmaxf(acc[rr] + twv, 0.f) * qv;
#pragma unroll
            for (int rr = 0; rr < 4; ++rr) part[rr] = dpp_reduce16(part[rr]);
            if (l15 == 0) {
                int row = mt * 16 + lg * 4;
                f32x4 v;
#pragma unroll
                for (int rr = 0; rr < 4; ++rr)
                    v[rr] = (row + rr < T_HIST) ? part[rr] : -1e30f;
                *(f32x4*)&s_logits[w][row] = v;
            }
        }
        __syncthreads();  // B3

        // ---- softmax over T (R9 verbatim) ----
        float lv = -1e30f;
        if (tid < T_PAD) {
            lv = s_logits[0][tid] + s_logits[1][tid] + s_logits[2][tid] + s_logits[3][tid]
               + s_logits[4][tid] + s_logits[5][tid] + s_logits[6][tid] + s_logits[7][tid];
        }
        float m = lv;
#pragma unroll
        for (int off = 32; off >= 1; off >>= 1)
            m = fmaxf(m, __shfl_xor(m, off, 64));
        if (l == 0) s_red[w] = m;
        __syncthreads();  // B4
        float M = s_red[0];
#pragma unroll
        for (int k = 1; k < 8; ++k) M = fmaxf(M, s_red[k]);
        float e = (tid < T_PAD) ? __expf(lv - M) : 0.f;
        if (tid < T_PAD) s_scores[tid] = e;
        float sm = e;
#pragma unroll
        for (int off = 32; off >= 1; off >>= 1)
            sm += __shfl_xor(sm, off, 64);
        if (l == 0) s_red[8 + w] = sm;
        __syncthreads();  // B5
        float S = s_red[8];
#pragma unroll
        for (int k = 9; k < 16; ++k) S += s_red[k];

        // ---- pass 2 from exact f32 registers (both halves) ----
        f32x4 acc2 = vzero;
#pragma unroll
        for (int k = 0; k < 7; ++k) {
            float sc = s_scores[r + 16 * k];
#pragma unroll
            for (int rr = 0; rr < 4; ++rr)
                acc2[rr] = fmaf(sc, sH0[k][rr], acc2[rr]);
        }
#pragma unroll
        for (int k = 0; k < 5; ++k) {
            float sc = s_scores[112 + r + 16 * k];
#pragma unroll
            for (int rr = 0; rr < 4; ++rr)
                acc2[rr] = fmaf(sc, sH1[k][rr], acc2[rr]);
        }
        if (tid < 256) {
            float sc = s_scores[192 + r];
#pragma unroll
            for (int rr = 0; rr < 4; ++rr)
                acc2[rr] = fmaf(sc, sH1[5][rr], acc2[rr]);
        }
        *(f32x4*)&s_p2[r][c_log * 4] = acc2;
        __syncthreads();  // B6
        if (tid < 128) {
            float o = 0.f;
#pragma unroll
            for (int k = 0; k < 16; ++k) o += s_p2[k][tid];
            out[(size_t)b * D_EMB + tid] = o / S;
        }

        // ---- issue H0 + tw of next tile (burst #1, at body bottom) ----
        if (i + 1 < ITERS) {
            const f32x4* gn = ghist + (size_t)(b + 1) * NG;
#pragma unroll
            for (int k = 0; k < 7; ++k) sH0[k] = gn[base_g + k * 512];
            if (tid < 128) twstg = TW[(size_t)(b + 1) * D_EMB + tid];
        }
    }
}

extern "C" void kernel_launch(void* const* d_in, const int* in_sizes, int n_in,
                              void* d_out, int out_size, void* d_ws, size_t ws_size,
                              hipStream_t stream) {
    const float* target = (const float*)d_in[0];
    const float* hist   = (const float*)d_in[1];
    const float* Wk     = (const float*)d_in[2];
    const float* Wb     = (const float*)d_in[3];
    const float* qk     = (const float*)d_in[4];
    float* out = (float*)d_out;

    short* wfrag = (short*)d_ws;                   // 32 KB
    float* TW    = (float*)((char*)d_ws + 32768);  // 8 MB

    pack_w_kernel<<<dim3(8), dim3(256), 0, stream>>>(Wk, wfrag);
    tw_kernel<<<dim3(2048), dim3(128), 0, stream>>>(target, Wk, Wb, TW);
    attn_main<<<dim3(NBLK), dim3(512), 0, stream>>>(hist, TW, qk, wfrag, out);
}